// Round 1
// baseline (254.737 us; speedup 1.0000x reference)
//
#include <hip/hip_runtime.h>
#include <cstdint>
#include <cstddef>

typedef unsigned short u16;

#define S_LEN 2048
#define EMB   1024
#define HID   1024
#define NB    4

#define BM 128
#define BN 128
#define BK 32

using bf16x8 = __attribute__((ext_vector_type(8))) __bf16;
using f32x4  = __attribute__((ext_vector_type(4))) float;

// ---------- helpers ----------

__device__ __forceinline__ u16 f2bf(float f) {
  union { float f; uint32_t u; } c; c.f = f;
  uint32_t u = c.u;
  uint32_t r = (u + 0x7fffu + ((u >> 16) & 1u)) >> 16;  // RNE
  return (u16)r;
}

// async global->LDS, 16B per lane. LDS dest = wave-uniform base + lane*16.
__device__ __forceinline__ void gld_lds16(const u16* g, u16* l) {
  auto gp = (const __attribute__((address_space(1))) uint32_t*)(uintptr_t)(const void*)g;
  auto lp = (__attribute__((address_space(3))) uint32_t*)(uintptr_t)(void*)l;
  __builtin_amdgcn_global_load_lds(gp, lp, 16, 0, 0);
}

// ---------- fp32 -> bf16 convert (vectorized, grid-stride) ----------

__global__ void cvt_f32_bf16(const float* __restrict__ in, u16* __restrict__ out, int n4) {
  int i = blockIdx.x * blockDim.x + threadIdx.x;
  int stride = gridDim.x * blockDim.x;
  for (; i < n4; i += stride) {
    float4 v = reinterpret_cast<const float4*>(in)[i];
    ushort4 o = make_ushort4(f2bf(v.x), f2bf(v.y), f2bf(v.z), f2bf(v.w));
    reinterpret_cast<ushort4*>(out)[i] = o;
  }
}

// ---------- GEMM: C[M,N] = A[M,K] * B[N,K]^T  (m97 structure) ----------
// EPI 0: bf16 out, +bias               (Q/K projections)
// EPI 1: bf16 out transposed per batch, +bias  -> VT[b][n][s]  (V projection)
// EPI 2: f32 out, *scale, causal mask col>row -> -1e30   (scores)
// EPI 3: f32 out                        (PV -> final output)

template<int EPI>
__global__ __launch_bounds__(256)
void gemm_bt(const u16* __restrict__ A, const u16* __restrict__ B, void* __restrict__ Cv,
             const float* __restrict__ bias,
             int M, int N, int K, long sA, long sB, long sC, float scale)
{
  const int z = blockIdx.z;
  A += (long)z * sA;
  B += (long)z * sB;

  __shared__ __align__(16) u16 As[BM * BK];   // 8 KB
  __shared__ __align__(16) u16 Bs[BN * BK];   // 8 KB

  const int t    = threadIdx.x;
  const int lane = t & 63;
  const int wave = t >> 6;
  const int wr   = wave >> 1, wc = wave & 1;
  const int bm   = blockIdx.y * BM, bn = blockIdx.x * BN;

  f32x4 acc[4][4] = {};

  // staging: thread t loads 8 bf16 (16B); 4 threads per 32-col row
  const int r  = t >> 2, c8 = (t & 3) * 8;
  const u16* gA = A + (long)(bm + r) * K + c8;
  const u16* gB = B + (long)(bn + r) * K + c8;
  u16* sA0 = As + wave * 512;   // lane*8 elements appended by HW
  u16* sB0 = Bs + wave * 512;

  // fragment read offsets (A and B operands share the same lane mapping)
  const int lr = lane & 15;
  const int kg = lane >> 4;
  const int aoff = (wr * 64 + lr) * BK + kg * 8;
  const int boff = (wc * 64 + lr) * BK + kg * 8;

  for (int kt = 0; kt < K; kt += BK) {
    gld_lds16(gA,                sA0);
    gld_lds16(gA + 64 * (long)K, sA0 + 2048);
    gld_lds16(gB,                sB0);
    gld_lds16(gB + 64 * (long)K, sB0 + 2048);
    gA += BK; gB += BK;
    __syncthreads();   // drains vmcnt(0) before barrier -> LDS tile ready

    bf16x8 af[4], bf[4];
#pragma unroll
    for (int i = 0; i < 4; ++i)
      af[i] = *reinterpret_cast<const bf16x8*>(&As[aoff + i * 16 * BK]);
#pragma unroll
    for (int j = 0; j < 4; ++j)
      bf[j] = *reinterpret_cast<const bf16x8*>(&Bs[boff + j * 16 * BK]);
#pragma unroll
    for (int i = 0; i < 4; ++i)
#pragma unroll
      for (int j = 0; j < 4; ++j)
        acc[i][j] = __builtin_amdgcn_mfma_f32_16x16x32_bf16(af[i], bf[j], acc[i][j], 0, 0, 0);
    __syncthreads();   // protect LDS before next stage
  }

  // epilogue: C mapping col=lane&15, row=(lane>>4)*4+reg  [m89/m91 verified]
  const int cl = lane & 15;
  const int rg = lane >> 4;

  if constexpr (EPI == 0) {            // bf16 + bias
    u16* C = (u16*)Cv;
#pragma unroll
    for (int j = 0; j < 4; ++j) {
      const int col = bn + wc * 64 + j * 16 + cl;
      const float bb = bias[col];
#pragma unroll
      for (int i = 0; i < 4; ++i) {
        const int row0 = bm + wr * 64 + i * 16 + rg * 4;
#pragma unroll
        for (int q = 0; q < 4; ++q)
          C[(long)(row0 + q) * N + col] = f2bf(acc[i][j][q] + bb);
      }
    }
  } else if constexpr (EPI == 1) {     // bf16 + bias, transposed per batch: VT[b][col][s]
    u16* C = (u16*)Cv;
#pragma unroll
    for (int j = 0; j < 4; ++j) {
      const int col = bn + wc * 64 + j * 16 + cl;
      const float bb = bias[col];
#pragma unroll
      for (int i = 0; i < 4; ++i) {
        const int row0 = bm + wr * 64 + i * 16 + rg * 4;    // row0 % 4 == 0
        const int b = row0 >> 11;                            // batch
        const int s = row0 & (S_LEN - 1);
        const long base = ((long)b * HID + col) * S_LEN + s; // 4 consecutive s
        ushort4 o = make_ushort4(f2bf(acc[i][j][0] + bb), f2bf(acc[i][j][1] + bb),
                                 f2bf(acc[i][j][2] + bb), f2bf(acc[i][j][3] + bb));
        *reinterpret_cast<ushort4*>((u16*)C + base) = o;
      }
    }
  } else if constexpr (EPI == 2) {     // f32, scaled, causal mask
    float* C = (float*)Cv + (long)z * sC;
#pragma unroll
    for (int j = 0; j < 4; ++j) {
      const int col = bn + wc * 64 + j * 16 + cl;
#pragma unroll
      for (int i = 0; i < 4; ++i) {
        const int row0 = bm + wr * 64 + i * 16 + rg * 4;
#pragma unroll
        for (int q = 0; q < 4; ++q) {
          const int row = row0 + q;
          float v = acc[i][j][q] * scale;
          if (col > row) v = -1e30f;
          C[(long)row * N + col] = v;
        }
      }
    }
  } else {                             // f32 plain (final output)
    float* C = (float*)Cv + (long)z * sC;
#pragma unroll
    for (int j = 0; j < 4; ++j) {
      const int col = bn + wc * 64 + j * 16 + cl;
#pragma unroll
      for (int i = 0; i < 4; ++i) {
        const int row0 = bm + wr * 64 + i * 16 + rg * 4;
#pragma unroll
        for (int q = 0; q < 4; ++q)
          C[(long)(row0 + q) * N + col] = acc[i][j][q];
      }
    }
  }
}

// ---------- causal row softmax: fp32 scores -> bf16 P ----------
// one block per row; 256 threads; 2048 cols (8 per thread)

__global__ __launch_bounds__(256)
void softmax_causal(const float* __restrict__ Sc, u16* __restrict__ P, long sS, long sP)
{
  const int row = blockIdx.x;
  const int z   = blockIdx.y;
  const float* srow = Sc + (long)z * sS + (long)row * S_LEN;
  u16*        prow = P  + (long)z * sP + (long)row * S_LEN;
  const int t = threadIdx.x;
  const int lane = t & 63, wave = t >> 6;

  float4 v0 = reinterpret_cast<const float4*>(srow)[t];
  float4 v1 = reinterpret_cast<const float4*>(srow)[t + 256];

  float mx = fmaxf(fmaxf(fmaxf(v0.x, v0.y), fmaxf(v0.z, v0.w)),
                   fmaxf(fmaxf(v1.x, v1.y), fmaxf(v1.z, v1.w)));

  __shared__ float red[8];
#pragma unroll
  for (int off = 32; off; off >>= 1) mx = fmaxf(mx, __shfl_down(mx, off));
  if (lane == 0) red[wave] = mx;
  __syncthreads();
  mx = fmaxf(fmaxf(red[0], red[1]), fmaxf(red[2], red[3]));

  float e[8];
  e[0] = __expf(v0.x - mx); e[1] = __expf(v0.y - mx);
  e[2] = __expf(v0.z - mx); e[3] = __expf(v0.w - mx);
  e[4] = __expf(v1.x - mx); e[5] = __expf(v1.y - mx);
  e[6] = __expf(v1.z - mx); e[7] = __expf(v1.w - mx);

  float sm = ((e[0] + e[1]) + (e[2] + e[3])) + ((e[4] + e[5]) + (e[6] + e[7]));
#pragma unroll
  for (int off = 32; off; off >>= 1) sm += __shfl_down(sm, off);
  if (lane == 0) red[4 + wave] = sm;
  __syncthreads();
  sm = (red[4] + red[5]) + (red[6] + red[7]);

  const float inv = 1.0f / sm;
  ushort4 o0 = make_ushort4(f2bf(e[0]*inv), f2bf(e[1]*inv), f2bf(e[2]*inv), f2bf(e[3]*inv));
  ushort4 o1 = make_ushort4(f2bf(e[4]*inv), f2bf(e[5]*inv), f2bf(e[6]*inv), f2bf(e[7]*inv));
  reinterpret_cast<ushort4*>(prow)[t]       = o0;
  reinterpret_cast<ushort4*>(prow)[t + 256] = o1;
}

// ---------- launch ----------

extern "C" void kernel_launch(void* const* d_in, const int* in_sizes, int n_in,
                              void* d_out, int out_size, void* d_ws, size_t ws_size,
                              hipStream_t stream)
{
  const float* x  = (const float*)d_in[0];
  const float* Wq = (const float*)d_in[1];
  const float* bq = (const float*)d_in[2];
  const float* Wk = (const float*)d_in[3];
  const float* bk = (const float*)d_in[4];
  const float* Wv = (const float*)d_in[5];
  const float* bv = (const float*)d_in[6];
  float* out = (float*)d_out;

  const long M = (long)NB * S_LEN;  // 8192

  u16* xb  = (u16*)d_ws;
  u16* wqb = xb  + M * EMB;
  u16* wkb = wqb + (long)HID * EMB;
  u16* wvb = wkb + (long)HID * EMB;
  u16* Qb  = wvb + (long)HID * EMB;
  u16* Kb  = Qb  + M * HID;
  u16* VT  = Kb  + M * HID;
  char* rest = (char*)(VT + M * HID);
  const size_t used  = (size_t)(rest - (char*)d_ws);
  const size_t ssz   = (size_t)S_LEN * S_LEN;
  const size_t need4 = used + (size_t)NB * ssz * 4 + (size_t)NB * ssz * 2;
  const int nb = (ws_size >= need4) ? NB : 1;
  float* scores = (float*)rest;
  u16*   P      = (u16*)(rest + (size_t)nb * ssz * 4);

  // fp32 -> bf16
  cvt_f32_bf16<<<2048, 256, 0, stream>>>(x,  xb,  (int)(M * EMB / 4));
  cvt_f32_bf16<<<512,  256, 0, stream>>>(Wq, wqb, HID * EMB / 4);
  cvt_f32_bf16<<<512,  256, 0, stream>>>(Wk, wkb, HID * EMB / 4);
  cvt_f32_bf16<<<512,  256, 0, stream>>>(Wv, wvb, HID * EMB / 4);

  // projections (M=8192, N=1024, K=1024)
  dim3 gp(HID / BN, M / BM, 1);
  gemm_bt<0><<<gp, 256, 0, stream>>>(xb, wqb, Qb, bq, (int)M, HID, EMB, 0, 0, 0, 1.0f);
  gemm_bt<0><<<gp, 256, 0, stream>>>(xb, wkb, Kb, bk, (int)M, HID, EMB, 0, 0, 0, 1.0f);
  gemm_bt<1><<<gp, 256, 0, stream>>>(xb, wvb, VT, bv, (int)M, HID, EMB, 0, 0, 0, 1.0f);

  const float scale = 0.03125f;  // 1/sqrt(1024)

  if (nb == NB) {
    dim3 gs(S_LEN / BN, S_LEN / BM, NB);
    gemm_bt<2><<<gs, 256, 0, stream>>>(Qb, Kb, scores, nullptr, S_LEN, S_LEN, HID,
                                       (long)S_LEN * HID, (long)S_LEN * HID, (long)ssz, scale);
    softmax_causal<<<dim3(S_LEN, NB), 256, 0, stream>>>(scores, P, (long)ssz, (long)ssz);
    dim3 gv(HID / BN, S_LEN / BM, NB);
    gemm_bt<3><<<gv, 256, 0, stream>>>(P, VT, out, nullptr, S_LEN, HID, S_LEN,
                                       (long)ssz, (long)HID * S_LEN, (long)S_LEN * HID, 1.0f);
  } else {
    for (int b = 0; b < NB; ++b) {
      const u16* Qbb = Qb + (long)b * S_LEN * HID;
      const u16* Kbb = Kb + (long)b * S_LEN * HID;
      const u16* VTb = VT + (long)b * HID * S_LEN;
      float* outb = out + (long)b * S_LEN * HID;
      dim3 gs(S_LEN / BN, S_LEN / BM, 1);
      gemm_bt<2><<<gs, 256, 0, stream>>>(Qbb, Kbb, scores, nullptr, S_LEN, S_LEN, HID, 0, 0, 0, scale);
      softmax_causal<<<dim3(S_LEN, 1), 256, 0, stream>>>(scores, P, 0, 0);
      dim3 gv(HID / BN, S_LEN / BM, 1);
      gemm_bt<3><<<gv, 256, 0, stream>>>(P, VTb, outb, nullptr, S_LEN, HID, S_LEN, 0, 0, 0, 1.0f);
    }
  }
}

// Round 2
// 219.233 us; speedup vs baseline: 1.1619x; 1.1619x over previous
//
#include <hip/hip_runtime.h>
#include <cstdint>
#include <cstddef>
#include <math.h>

typedef unsigned short u16;

#define S_LEN 2048
#define EMB   1024
#define HID   1024
#define NB    4

#define BM 128
#define BN 128
#define BK 32

using bf16x8 = __attribute__((ext_vector_type(8))) __bf16;
using f32x4  = __attribute__((ext_vector_type(4))) float;

// ---------- helpers ----------

__device__ __forceinline__ u16 f2bf(float f) {
  union { float f; uint32_t u; } c; c.f = f;
  uint32_t u = c.u;
  uint32_t r = (u + 0x7fffu + ((u >> 16) & 1u)) >> 16;  // RNE
  return (u16)r;
}

// async global->LDS, 16B per lane. LDS dest = wave-uniform base + lane*16.
__device__ __forceinline__ void gld_lds16(const u16* g, u16* l) {
  auto gp = (const __attribute__((address_space(1))) uint32_t*)(uintptr_t)(const void*)g;
  auto lp = (__attribute__((address_space(3))) uint32_t*)(uintptr_t)(void*)l;
  __builtin_amdgcn_global_load_lds(gp, lp, 16, 0, 0);
}

// ---------- fp32 -> bf16 convert (vectorized, grid-stride) ----------

__global__ void cvt_f32_bf16(const float* __restrict__ in, u16* __restrict__ out, int n4) {
  int i = blockIdx.x * blockDim.x + threadIdx.x;
  int stride = gridDim.x * blockDim.x;
  for (; i < n4; i += stride) {
    float4 v = reinterpret_cast<const float4*>(in)[i];
    ushort4 o = make_ushort4(f2bf(v.x), f2bf(v.y), f2bf(v.z), f2bf(v.w));
    reinterpret_cast<ushort4*>(out)[i] = o;
  }
}

// ---------- GEMM: C[M,N] = A[M,K] * B[N,K]^T  (m97 structure) ----------
// EPI 2: f32 out, *scale, causal mask col>row -> -1e30; TRIANGULAR grid (scores)
// EPI 3: f32 out; K-loop stops at bm+BM (causal PV -> final output)
// EPI 4: fused QKV projection epilogue: route per 128-col block to Q / K / VT

template<int EPI>
__global__ __launch_bounds__(256)
void gemm_bt(const u16* __restrict__ A, const u16* __restrict__ B, void* __restrict__ Cv,
             const float* __restrict__ b0, const float* __restrict__ b1,
             const float* __restrict__ b2, void* __restrict__ aux,
             int M, int N, int K, long sA, long sB, long sC, float scale)
{
  const int z = blockIdx.z;
  A += (long)z * sA;
  B += (long)z * sB;

  __shared__ __align__(16) u16 As[BM * BK];   // 8 KB
  __shared__ __align__(16) u16 Bs[BN * BK];   // 8 KB

  const int t    = threadIdx.x;
  const int lane = t & 63;
  const int wave = t >> 6;
  const int wr   = wave >> 1, wc = wave & 1;

  int bm, bn;
  if constexpr (EPI == 2) {
    // lower-triangular block decode: x -> (bi, bj), bj <= bi
    const int x = blockIdx.x;
    int bi = (int)((sqrtf(8.0f * (float)x + 1.0f) - 1.0f) * 0.5f);
    while ((bi + 1) * (bi + 2) / 2 <= x) ++bi;
    while (bi * (bi + 1) / 2 > x) --bi;
    const int bj = x - bi * (bi + 1) / 2;
    bm = bi * BM; bn = bj * BN;
  } else {
    bm = blockIdx.y * BM; bn = blockIdx.x * BN;
  }

  int kend = K;
  if constexpr (EPI == 3) kend = bm + BM;   // causal: P[q, c>=bm+BM] == 0 for q in tile

  f32x4 acc[4][4] = {};

  // staging: thread t loads 8 bf16 (16B); 4 threads per 32-col row
  const int r  = t >> 2, c8 = (t & 3) * 8;
  const u16* gA = A + (long)(bm + r) * K + c8;
  const u16* gB = B + (long)(bn + r) * K + c8;
  u16* sA0 = As + wave * 512;   // lane*8 elements appended by HW
  u16* sB0 = Bs + wave * 512;

  // fragment read offsets (A and B operands share the same lane mapping)
  const int lr = lane & 15;
  const int kg = lane >> 4;
  const int aoff = (wr * 64 + lr) * BK + kg * 8;
  const int boff = (wc * 64 + lr) * BK + kg * 8;

  for (int kt = 0; kt < kend; kt += BK) {
    gld_lds16(gA,                sA0);
    gld_lds16(gA + 64 * (long)K, sA0 + 2048);
    gld_lds16(gB,                sB0);
    gld_lds16(gB + 64 * (long)K, sB0 + 2048);
    gA += BK; gB += BK;
    __syncthreads();   // drains vmcnt(0) before barrier -> LDS tile ready

    bf16x8 af[4], bf[4];
#pragma unroll
    for (int i = 0; i < 4; ++i)
      af[i] = *reinterpret_cast<const bf16x8*>(&As[aoff + i * 16 * BK]);
#pragma unroll
    for (int j = 0; j < 4; ++j)
      bf[j] = *reinterpret_cast<const bf16x8*>(&Bs[boff + j * 16 * BK]);
#pragma unroll
    for (int i = 0; i < 4; ++i)
#pragma unroll
      for (int j = 0; j < 4; ++j)
        acc[i][j] = __builtin_amdgcn_mfma_f32_16x16x32_bf16(af[i], bf[j], acc[i][j], 0, 0, 0);
    __syncthreads();   // protect LDS before next stage
  }

  // epilogue: C mapping col=lane&15, row=(lane>>4)*4+reg  [m89/m91 verified]
  const int cl = lane & 15;
  const int rg = lane >> 4;

  if constexpr (EPI == 2) {            // f32, scaled, causal mask
    float* C = (float*)Cv + (long)z * sC;
#pragma unroll
    for (int j = 0; j < 4; ++j) {
      const int col = bn + wc * 64 + j * 16 + cl;
#pragma unroll
      for (int i = 0; i < 4; ++i) {
        const int row0 = bm + wr * 64 + i * 16 + rg * 4;
#pragma unroll
        for (int q = 0; q < 4; ++q) {
          const int row = row0 + q;
          float v = acc[i][j][q] * scale;
          if (col > row) v = -1e30f;
          C[(long)row * N + col] = v;
        }
      }
    }
  } else if constexpr (EPI == 3) {     // f32 plain (final output)
    float* C = (float*)Cv + (long)z * sC;
#pragma unroll
    for (int j = 0; j < 4; ++j) {
      const int col = bn + wc * 64 + j * 16 + cl;
#pragma unroll
      for (int i = 0; i < 4; ++i) {
        const int row0 = bm + wr * 64 + i * 16 + rg * 4;
#pragma unroll
        for (int q = 0; q < 4; ++q)
          C[(long)(row0 + q) * N + col] = acc[i][j][q];
      }
    }
  } else {                             // EPI 4: fused QKV routing
    const int sel = bn >> 10;          // 0=Q, 1=K, 2=V   (block-uniform)
    const float* bias = (sel == 0) ? b0 : (sel == 1) ? b1 : b2;
    u16* QK = (u16*)Cv;                // Q base; K at +M*HID
    u16* VT = (u16*)aux;
#pragma unroll
    for (int j = 0; j < 4; ++j) {
      const int col = bn + wc * 64 + j * 16 + cl;
      const int h   = col & (HID - 1);
      const float bb = bias[h];
#pragma unroll
      for (int i = 0; i < 4; ++i) {
        const int row0 = bm + wr * 64 + i * 16 + rg * 4;
        if (sel < 2) {
          u16* dst = QK + (long)sel * (long)M * HID + (long)row0 * HID + h;
#pragma unroll
          for (int q = 0; q < 4; ++q)
            dst[(long)q * HID] = f2bf(acc[i][j][q] + bb);
        } else {
          const int b = row0 >> 11;                 // batch (row0 % 4 == 0)
          const int s = row0 & (S_LEN - 1);
          const long base = ((long)b * HID + h) * S_LEN + s;
          ushort4 o = make_ushort4(f2bf(acc[i][j][0] + bb), f2bf(acc[i][j][1] + bb),
                                   f2bf(acc[i][j][2] + bb), f2bf(acc[i][j][3] + bb));
          *reinterpret_cast<ushort4*>(VT + base) = o;
        }
      }
    }
  }
}

// ---------- causal row softmax: fp32 scores -> bf16 P ----------
// one block per row; 256 threads; processes cols < kend = ((row>>7)+1)*128

__global__ __launch_bounds__(256)
void softmax_causal(const float* __restrict__ Sc, u16* __restrict__ P, long sS, long sP)
{
  const int row  = blockIdx.x;
  const int z    = blockIdx.y;
  const int kend = ((row >> 7) + 1) << 7;
  const float* srow = Sc + (long)z * sS + (long)row * S_LEN;
  u16*        prow = P  + (long)z * sP + (long)row * S_LEN;
  const int t = threadIdx.x;
  const int lane = t & 63, wave = t >> 6;

  const bool p0 = (4 * t) < kend;
  const bool p1 = (1024 + 4 * t) < kend;

  float4 v0 = make_float4(-1e30f, -1e30f, -1e30f, -1e30f);
  float4 v1 = v0;
  if (p0) v0 = reinterpret_cast<const float4*>(srow)[t];
  if (p1) v1 = reinterpret_cast<const float4*>(srow)[t + 256];

  float mx = fmaxf(fmaxf(fmaxf(v0.x, v0.y), fmaxf(v0.z, v0.w)),
                   fmaxf(fmaxf(v1.x, v1.y), fmaxf(v1.z, v1.w)));

  __shared__ float red[8];
#pragma unroll
  for (int off = 32; off; off >>= 1) mx = fmaxf(mx, __shfl_down(mx, off));
  if (lane == 0) red[wave] = mx;
  __syncthreads();
  mx = fmaxf(fmaxf(red[0], red[1]), fmaxf(red[2], red[3]));

  float e[8];
  e[0] = __expf(v0.x - mx); e[1] = __expf(v0.y - mx);
  e[2] = __expf(v0.z - mx); e[3] = __expf(v0.w - mx);
  e[4] = __expf(v1.x - mx); e[5] = __expf(v1.y - mx);
  e[6] = __expf(v1.z - mx); e[7] = __expf(v1.w - mx);

  float sm = ((e[0] + e[1]) + (e[2] + e[3])) + ((e[4] + e[5]) + (e[6] + e[7]));
#pragma unroll
  for (int off = 32; off; off >>= 1) sm += __shfl_down(sm, off);
  if (lane == 0) red[4 + wave] = sm;
  __syncthreads();
  sm = (red[4] + red[5]) + (red[6] + red[7]);

  const float inv = 1.0f / sm;
  if (p0) {
    ushort4 o0 = make_ushort4(f2bf(e[0]*inv), f2bf(e[1]*inv), f2bf(e[2]*inv), f2bf(e[3]*inv));
    reinterpret_cast<ushort4*>(prow)[t] = o0;
  }
  if (p1) {
    ushort4 o1 = make_ushort4(f2bf(e[4]*inv), f2bf(e[5]*inv), f2bf(e[6]*inv), f2bf(e[7]*inv));
    reinterpret_cast<ushort4*>(prow)[t + 256] = o1;
  }
}

// ---------- launch ----------

extern "C" void kernel_launch(void* const* d_in, const int* in_sizes, int n_in,
                              void* d_out, int out_size, void* d_ws, size_t ws_size,
                              hipStream_t stream)
{
  const float* x  = (const float*)d_in[0];
  const float* Wq = (const float*)d_in[1];
  const float* bq = (const float*)d_in[2];
  const float* Wk = (const float*)d_in[3];
  const float* bk = (const float*)d_in[4];
  const float* Wv = (const float*)d_in[5];
  const float* bv = (const float*)d_in[6];
  float* out = (float*)d_out;

  const long M = (long)NB * S_LEN;  // 8192

  u16* xb  = (u16*)d_ws;
  u16* wqb = xb  + M * EMB;         // wq/wk/wv contiguous -> fused [3072,1024]
  u16* wkb = wqb + (long)HID * EMB;
  u16* wvb = wkb + (long)HID * EMB;
  u16* Qb  = wvb + (long)HID * EMB; // Q then K contiguous
  u16* Kb  = Qb  + M * HID;
  u16* VT  = Kb  + M * HID;
  char* rest = (char*)(VT + M * HID);
  const size_t used  = (size_t)(rest - (char*)d_ws);
  const size_t ssz   = (size_t)S_LEN * S_LEN;
  const size_t need4 = used + (size_t)NB * ssz * 4 + (size_t)NB * ssz * 2;
  const int nb = (ws_size >= need4) ? NB : 1;
  float* scores = (float*)rest;
  u16*   P      = (u16*)(rest + (size_t)nb * ssz * 4);

  // fp32 -> bf16
  cvt_f32_bf16<<<2048, 256, 0, stream>>>(x,  xb,  (int)(M * EMB / 4));
  cvt_f32_bf16<<<512,  256, 0, stream>>>(Wq, wqb, HID * EMB / 4);
  cvt_f32_bf16<<<512,  256, 0, stream>>>(Wk, wkb, HID * EMB / 4);
  cvt_f32_bf16<<<512,  256, 0, stream>>>(Wv, wvb, HID * EMB / 4);

  // fused QKV projection: M=8192, N=3072, K=1024
  {
    dim3 gp(3 * HID / BN, M / BM, 1);
    gemm_bt<4><<<gp, 256, 0, stream>>>(xb, wqb, Qb, bq, bk, bv, VT,
                                       (int)M, 3 * HID, EMB, 0, 0, 0, 1.0f);
  }

  const float scale = 0.03125f;  // 1/sqrt(1024)
  const int NT  = S_LEN / BM;              // 16 block-rows
  const int TRI = NT * (NT + 1) / 2;       // 136 lower-tri blocks

  if (nb == NB) {
    dim3 gs(TRI, 1, NB);
    gemm_bt<2><<<gs, 256, 0, stream>>>(Qb, Kb, scores, nullptr, nullptr, nullptr, nullptr,
                                       S_LEN, S_LEN, HID,
                                       (long)S_LEN * HID, (long)S_LEN * HID, (long)ssz, scale);
    softmax_causal<<<dim3(S_LEN, NB), 256, 0, stream>>>(scores, P, (long)ssz, (long)ssz);
    dim3 gv(HID / BN, S_LEN / BM, NB);
    gemm_bt<3><<<gv, 256, 0, stream>>>(P, VT, out, nullptr, nullptr, nullptr, nullptr,
                                       S_LEN, HID, S_LEN,
                                       (long)ssz, (long)HID * S_LEN, (long)S_LEN * HID, 1.0f);
  } else {
    for (int b = 0; b < NB; ++b) {
      const u16* Qbb = Qb + (long)b * S_LEN * HID;
      const u16* Kbb = Kb + (long)b * S_LEN * HID;
      const u16* VTb = VT + (long)b * HID * S_LEN;
      float* outb = out + (long)b * S_LEN * HID;
      dim3 gs(TRI, 1, 1);
      gemm_bt<2><<<gs, 256, 0, stream>>>(Qbb, Kbb, scores, nullptr, nullptr, nullptr, nullptr,
                                         S_LEN, S_LEN, HID, 0, 0, 0, scale);
      softmax_causal<<<dim3(S_LEN, 1), 256, 0, stream>>>(scores, P, 0, 0);
      dim3 gv(HID / BN, S_LEN / BM, 1);
      gemm_bt<3><<<gv, 256, 0, stream>>>(P, VTb, outb, nullptr, nullptr, nullptr, nullptr,
                                         S_LEN, HID, S_LEN, 0, 0, 0, 1.0f);
    }
  }
}

// Round 3
// 204.979 us; speedup vs baseline: 1.2427x; 1.0695x over previous
//
#include <hip/hip_runtime.h>
#include <cstdint>
#include <cstddef>
#include <math.h>

typedef unsigned short u16;

#define S_LEN 2048
#define EMB   1024
#define HID   1024
#define NB    4

// 256x256 tile, BK=32, 8 waves (2M x 4N), 4 LDS buffers, depth-3 prefetch
#define BM 256
#define BN 256
#define BK 32

using bf16x8 = __attribute__((ext_vector_type(8))) __bf16;
using f32x4  = __attribute__((ext_vector_type(4))) float;

// ---------- helpers ----------

__device__ __forceinline__ u16 f2bf(float f) {
  union { float f; uint32_t u; } c; c.f = f;
  uint32_t u = c.u;
  uint32_t r = (u + 0x7fffu + ((u >> 16) & 1u)) >> 16;  // RNE
  return (u16)r;
}

// async global->LDS, 16B per lane. LDS dest = wave-uniform base + lane*16.
__device__ __forceinline__ void gld_lds16(const u16* g, u16* l) {
  auto gp = (const __attribute__((address_space(1))) uint32_t*)(uintptr_t)(const void*)g;
  auto lp = (__attribute__((address_space(3))) uint32_t*)(uintptr_t)(void*)l;
  __builtin_amdgcn_global_load_lds(gp, lp, 16, 0, 0);
}

// ---------- fp32 -> bf16 convert ----------

__global__ void cvt_f32_bf16(const float* __restrict__ in, u16* __restrict__ out, int n4) {
  int i = blockIdx.x * blockDim.x + threadIdx.x;
  int stride = gridDim.x * blockDim.x;
  for (; i < n4; i += stride) {
    float4 v = reinterpret_cast<const float4*>(in)[i];
    ushort4 o = make_ushort4(f2bf(v.x), f2bf(v.y), f2bf(v.z), f2bf(v.w));
    reinterpret_cast<ushort4*>(out)[i] = o;
  }
}

// ---------- 256^2 deep-pipelined GEMM: C[M,N] = A[M,K] * B[N,K]^T ----------
// EPI 2: f32 out, *scale, causal mask col>row -> -1e30; triangular grid (scores)
// EPI 3: f32 out; kend = bm+BM (causal PV -> final output)
// EPI 4: fused QKV routing epilogue (Q / K / V-transposed), +bias
//
// LDS: 4 buffers x (A 16KB + B 16KB) = 128 KB.
// Pipeline: tile t+3 staged during tile t's phases into buf[(t+3)&3], whose
// previous contents (tile t-1) were fully read last iteration (past barrier).
// s_waitcnt vmcnt(10) at each tile boundary: waits tile t's 4 loads, keeps
// 10 newer in flight (counted, never drains to 0). Uniform 4 loads/iter via
// clamped prefetch index.
// Swizzle (both-sides): logical (row, chunk) stored at physical chunk
// kg ^ f(row), f(row) = (row&3)^((row>>2)&3); applied to global source on
// stage and to ds_read address -> 2-way bank aliasing (free).

template<int EPI>
__global__ __launch_bounds__(512, 2)
void gemm256(const u16* __restrict__ A, const u16* __restrict__ B, void* __restrict__ Cv,
             const float* __restrict__ b0, const float* __restrict__ b1,
             const float* __restrict__ b2, void* __restrict__ aux,
             int M, int N, int K, long sA, long sB, long sC, float scale)
{
  const int z = blockIdx.z;
  A += (long)z * sA;
  B += (long)z * sB;

  __shared__ __align__(16) u16 smem[4 * 16384];   // 128 KB

  const int tid  = threadIdx.x;
  const int lane = tid & 63;
  const int wave = tid >> 6;
  const int wr   = wave >> 2;        // 0..1  (M split)
  const int wc   = wave & 3;         // 0..3  (N split)

  int bm, bn;
  if constexpr (EPI == 2) {
    const int x = blockIdx.x;
    int bi = (int)((sqrtf(8.0f * (float)x + 1.0f) - 1.0f) * 0.5f);
    while ((bi + 1) * (bi + 2) / 2 <= x) ++bi;
    while (bi * (bi + 1) / 2 > x) --bi;
    bm = bi * BM;
    bn = (x - bi * (bi + 1) / 2) * BN;
  } else {
    bm = blockIdx.y * BM; bn = blockIdx.x * BN;
  }

  int kend = K;
  if constexpr (EPI == 3) kend = bm + BM;
  const int NT = kend / BK;

  // ---- staging address precompute (2 steps per operand, 2 loads per step pair) ----
  const int r0  = tid >> 2;          // row within 128-row step
  const int pch = tid & 3;           // physical 16B chunk in 64B row
  const u16* gA[2]; const u16* gB[2];
#pragma unroll
  for (int s = 0; s < 2; ++s) {
    const int row = s * 128 + r0;
    const int lc  = pch ^ ((row & 3) ^ ((row >> 2) & 3));   // inverse-swizzled source chunk
    gA[s] = A + (long)(bm + row) * K + lc * 8;
    gB[s] = B + (long)(bn + row) * K + lc * 8;
  }

  // ---- fragment ds_read offsets (u16 units), swizzled ----
  const int lr  = lane & 15;
  const int kg  = lane >> 4;
  const int sch = kg ^ ((lr & 3) ^ ((lr >> 2) & 3));
  int aofs[8], bofs[4];
#pragma unroll
  for (int m = 0; m < 8; ++m) aofs[m] = (wr * 128 + m * 16 + lr) * 32 + sch * 8;
#pragma unroll
  for (int n = 0; n < 4; ++n) bofs[n] = 8192 + (wc * 64 + n * 16 + lr) * 32 + sch * 8;

  f32x4 acc[8][4] = {};

  // ---- prologue: stage tiles 0,1,2 into buffers 0,1,2 (12 loads/thread) ----
#pragma unroll
  for (int p = 0; p < 3; ++p) {
#pragma unroll
    for (int s = 0; s < 2; ++s) {
      gld_lds16(gA[s] + p * BK, smem + p * 16384 +        s * 4096 + wave * 512);
      gld_lds16(gB[s] + p * BK, smem + p * 16384 + 8192 + s * 4096 + wave * 512);
    }
  }

  // ---- main loop ----
  for (int t = 0; t < NT; ++t) {
    const u16* bufA = smem + (t & 3) * 16384;
    u16*       stg  = smem + ((t + 3) & 3) * 16384;
    const int  tp   = (t + 3 < NT) ? (t + 3) : (NT - 1);   // clamped: uniform vmcnt accounting
    const long ko   = (long)tp * BK;

    // ===== phase 1: stage step0, wait tile t, MFMA m0-3 =====
    gld_lds16(gA[0] + ko, stg +        wave * 512);
    gld_lds16(gB[0] + ko, stg + 8192 + wave * 512);
    asm volatile("s_waitcnt vmcnt(10)" ::: "memory");   // tile t landed; 10 newer in flight
    __builtin_amdgcn_s_barrier();
    asm volatile("" ::: "memory");

    bf16x8 a0[4], bb[4];
#pragma unroll
    for (int m = 0; m < 4; ++m) a0[m] = *reinterpret_cast<const bf16x8*>(bufA + aofs[m]);
#pragma unroll
    for (int n = 0; n < 4; ++n) bb[n] = *reinterpret_cast<const bf16x8*>(bufA + bofs[n]);
    __builtin_amdgcn_s_setprio(1);
#pragma unroll
    for (int m = 0; m < 4; ++m)
#pragma unroll
      for (int n = 0; n < 4; ++n)
        acc[m][n] = __builtin_amdgcn_mfma_f32_16x16x32_bf16(a0[m], bb[n], acc[m][n], 0, 0, 0);
    __builtin_amdgcn_s_setprio(0);
    __builtin_amdgcn_s_barrier();
    asm volatile("" ::: "memory");

    // ===== phase 2: stage step1, MFMA m4-7 (reuse bb) =====
    gld_lds16(gA[1] + ko, stg +        4096 + wave * 512);
    gld_lds16(gB[1] + ko, stg + 8192 + 4096 + wave * 512);

    bf16x8 a1[4];
#pragma unroll
    for (int m = 0; m < 4; ++m) a1[m] = *reinterpret_cast<const bf16x8*>(bufA + aofs[4 + m]);
    __builtin_amdgcn_s_setprio(1);
#pragma unroll
    for (int m = 0; m < 4; ++m)
#pragma unroll
      for (int n = 0; n < 4; ++n)
        acc[4 + m][n] = __builtin_amdgcn_mfma_f32_16x16x32_bf16(a1[m], bb[n], acc[4 + m][n], 0, 0, 0);
    __builtin_amdgcn_s_setprio(0);
    __builtin_amdgcn_s_barrier();
    asm volatile("" ::: "memory");
  }

  // ---- epilogue: C/D mapping col=lane&15, row=(lane>>4)*4+q ----
  if constexpr (EPI == 2) {            // f32, scaled, causal mask
    float* C = (float*)Cv + (long)z * sC;
#pragma unroll
    for (int n = 0; n < 4; ++n) {
      const int col = bn + wc * 64 + n * 16 + lr;
#pragma unroll
      for (int m = 0; m < 8; ++m) {
        const int row0 = bm + wr * 128 + m * 16 + kg * 4;
#pragma unroll
        for (int q = 0; q < 4; ++q) {
          const int row = row0 + q;
          float v = acc[m][n][q] * scale;
          if (col > row) v = -1e30f;
          C[(long)row * N + col] = v;
        }
      }
    }
  } else if constexpr (EPI == 3) {     // f32 plain (final output)
    float* C = (float*)Cv + (long)z * sC;
#pragma unroll
    for (int n = 0; n < 4; ++n) {
      const int col = bn + wc * 64 + n * 16 + lr;
#pragma unroll
      for (int m = 0; m < 8; ++m) {
        const int row0 = bm + wr * 128 + m * 16 + kg * 4;
#pragma unroll
        for (int q = 0; q < 4; ++q)
          C[(long)(row0 + q) * N + col] = acc[m][n][q];
      }
    }
  } else {                             // EPI 4: fused QKV routing
    const int sel = bn >> 10;          // 0=Q, 1=K, 2=V (block-uniform: 256 | 1024)
    const float* bias = (sel == 0) ? b0 : (sel == 1) ? b1 : b2;
    u16* QK = (u16*)Cv;
    u16* VT = (u16*)aux;
#pragma unroll
    for (int n = 0; n < 4; ++n) {
      const int col = bn + wc * 64 + n * 16 + lr;
      const int h   = col & (HID - 1);
      const float bbv = bias[h];
#pragma unroll
      for (int m = 0; m < 8; ++m) {
        const int row0 = bm + wr * 128 + m * 16 + kg * 4;
        if (sel < 2) {
          u16* dst = QK + (long)sel * (long)M * HID + (long)row0 * HID + h;
#pragma unroll
          for (int q = 0; q < 4; ++q)
            dst[(long)q * HID] = f2bf(acc[m][n][q] + bbv);
        } else {
          const int b = row0 >> 11;                 // batch (row0 % 4 == 0)
          const int s = row0 & (S_LEN - 1);
          ushort4 o = make_ushort4(f2bf(acc[m][n][0] + bbv), f2bf(acc[m][n][1] + bbv),
                                   f2bf(acc[m][n][2] + bbv), f2bf(acc[m][n][3] + bbv));
          *reinterpret_cast<ushort4*>(VT + ((long)b * HID + h) * S_LEN + s) = o;
        }
      }
    }
  }
}

// ---------- causal row softmax: fp32 scores -> bf16 P ----------
// processes cols < kend = 256-aligned causal boundary (masked cols give e=0,
// so P is zero-filled up to kend -> PV at BM=256 reads only written data)

__global__ __launch_bounds__(256)
void softmax_causal(const float* __restrict__ Sc, u16* __restrict__ P, long sS, long sP)
{
  const int row  = blockIdx.x;
  const int z    = blockIdx.y;
  const int kend = ((row >> 8) + 1) << 8;
  const float* srow = Sc + (long)z * sS + (long)row * S_LEN;
  u16*        prow = P  + (long)z * sP + (long)row * S_LEN;
  const int t = threadIdx.x;
  const int lane = t & 63, wave = t >> 6;

  const bool p0 = (4 * t) < kend;
  const bool p1 = (1024 + 4 * t) < kend;

  float4 v0 = make_float4(-1e30f, -1e30f, -1e30f, -1e30f);
  float4 v1 = v0;
  if (p0) v0 = reinterpret_cast<const float4*>(srow)[t];
  if (p1) v1 = reinterpret_cast<const float4*>(srow)[t + 256];

  float mx = fmaxf(fmaxf(fmaxf(v0.x, v0.y), fmaxf(v0.z, v0.w)),
                   fmaxf(fmaxf(v1.x, v1.y), fmaxf(v1.z, v1.w)));

  __shared__ float red[8];
#pragma unroll
  for (int off = 32; off; off >>= 1) mx = fmaxf(mx, __shfl_down(mx, off));
  if (lane == 0) red[wave] = mx;
  __syncthreads();
  mx = fmaxf(fmaxf(red[0], red[1]), fmaxf(red[2], red[3]));

  float e[8];
  e[0] = __expf(v0.x - mx); e[1] = __expf(v0.y - mx);
  e[2] = __expf(v0.z - mx); e[3] = __expf(v0.w - mx);
  e[4] = __expf(v1.x - mx); e[5] = __expf(v1.y - mx);
  e[6] = __expf(v1.z - mx); e[7] = __expf(v1.w - mx);

  float sm = ((e[0] + e[1]) + (e[2] + e[3])) + ((e[4] + e[5]) + (e[6] + e[7]));
#pragma unroll
  for (int off = 32; off; off >>= 1) sm += __shfl_down(sm, off);
  if (lane == 0) red[4 + wave] = sm;
  __syncthreads();
  sm = (red[4] + red[5]) + (red[6] + red[7]);

  const float inv = 1.0f / sm;
  if (p0) {
    ushort4 o0 = make_ushort4(f2bf(e[0]*inv), f2bf(e[1]*inv), f2bf(e[2]*inv), f2bf(e[3]*inv));
    reinterpret_cast<ushort4*>(prow)[t] = o0;
  }
  if (p1) {
    ushort4 o1 = make_ushort4(f2bf(e[4]*inv), f2bf(e[5]*inv), f2bf(e[6]*inv), f2bf(e[7]*inv));
    reinterpret_cast<ushort4*>(prow)[t + 256] = o1;
  }
}

// ---------- launch ----------

extern "C" void kernel_launch(void* const* d_in, const int* in_sizes, int n_in,
                              void* d_out, int out_size, void* d_ws, size_t ws_size,
                              hipStream_t stream)
{
  const float* x  = (const float*)d_in[0];
  const float* Wq = (const float*)d_in[1];
  const float* bq = (const float*)d_in[2];
  const float* Wk = (const float*)d_in[3];
  const float* bk = (const float*)d_in[4];
  const float* Wv = (const float*)d_in[5];
  const float* bv = (const float*)d_in[6];
  float* out = (float*)d_out;

  const long M = (long)NB * S_LEN;  // 8192

  u16* xb  = (u16*)d_ws;
  u16* wqb = xb  + M * EMB;         // wq/wk/wv contiguous -> fused [3072,1024]
  u16* wkb = wqb + (long)HID * EMB;
  u16* wvb = wkb + (long)HID * EMB;
  u16* Qb  = wvb + (long)HID * EMB; // Q then K contiguous
  u16* Kb  = Qb  + M * HID;
  u16* VT  = Kb  + M * HID;
  char* rest = (char*)(VT + M * HID);
  const size_t used  = (size_t)(rest - (char*)d_ws);
  const size_t ssz   = (size_t)S_LEN * S_LEN;
  const size_t need4 = used + (size_t)NB * ssz * 4 + (size_t)NB * ssz * 2;
  const int nb = (ws_size >= need4) ? NB : 1;
  float* scores = (float*)rest;
  u16*   P      = (u16*)(rest + (size_t)nb * ssz * 4);

  // fp32 -> bf16
  cvt_f32_bf16<<<2048, 256, 0, stream>>>(x,  xb,  (int)(M * EMB / 4));
  cvt_f32_bf16<<<512,  256, 0, stream>>>(Wq, wqb, HID * EMB / 4);
  cvt_f32_bf16<<<512,  256, 0, stream>>>(Wk, wkb, HID * EMB / 4);
  cvt_f32_bf16<<<512,  256, 0, stream>>>(Wv, wvb, HID * EMB / 4);

  // fused QKV projection: M=8192, N=3072, K=1024
  {
    dim3 gp(3 * HID / BN, M / BM, 1);
    gemm256<4><<<gp, 512, 0, stream>>>(xb, wqb, Qb, bq, bk, bv, VT,
                                       (int)M, 3 * HID, EMB, 0, 0, 0, 1.0f);
  }

  const float scale = 0.03125f;  // 1/sqrt(1024)
  const int NTb = S_LEN / BM;              // 8 block-rows
  const int TRI = NTb * (NTb + 1) / 2;     // 36 lower-tri blocks

  if (nb == NB) {
    dim3 gs(TRI, 1, NB);
    gemm256<2><<<gs, 512, 0, stream>>>(Qb, Kb, scores, nullptr, nullptr, nullptr, nullptr,
                                       S_LEN, S_LEN, HID,
                                       (long)S_LEN * HID, (long)S_LEN * HID, (long)ssz, scale);
    softmax_causal<<<dim3(S_LEN, NB), 256, 0, stream>>>(scores, P, (long)ssz, (long)ssz);
    dim3 gv(HID / BN, S_LEN / BM, NB);
    gemm256<3><<<gv, 512, 0, stream>>>(P, VT, out, nullptr, nullptr, nullptr, nullptr,
                                       S_LEN, HID, S_LEN,
                                       (long)ssz, (long)HID * S_LEN, (long)S_LEN * HID, 1.0f);
  } else {
    for (int b = 0; b < NB; ++b) {
      const u16* Qbb = Qb + (long)b * S_LEN * HID;
      const u16* Kbb = Kb + (long)b * S_LEN * HID;
      const u16* VTb = VT + (long)b * HID * S_LEN;
      float* outb = out + (long)b * S_LEN * HID;
      dim3 gs(TRI, 1, 1);
      gemm256<2><<<gs, 512, 0, stream>>>(Qbb, Kbb, scores, nullptr, nullptr, nullptr, nullptr,
                                         S_LEN, S_LEN, HID, 0, 0, 0, scale);
      softmax_causal<<<dim3(S_LEN, 1), 256, 0, stream>>>(scores, P, 0, 0);
      dim3 gv(HID / BN, S_LEN / BM, 1);
      gemm256<3><<<gv, 512, 0, stream>>>(P, VTb, outb, nullptr, nullptr, nullptr, nullptr,
                                         S_LEN, HID, S_LEN, 0, 0, 0, 1.0f);
    }
  }
}